// Round 1
// baseline (4614.990 us; speedup 1.0000x reference)
//
#include <hip/hip_runtime.h>

typedef __attribute__((ext_vector_type(4))) float f4;
typedef __attribute__((ext_vector_type(8))) short frag8;
typedef unsigned long long u64;
typedef unsigned int u32;
typedef unsigned short u16;

#define ALPHA 0.3f

// ---- ws layout (bytes) ----
#define WHH_OFF   0ull                 // 3072*1024 bf16 = 6291456
#define WIH_OFF   6291456ull           // 3072*128 bf16  = 786432
#define HBUF_OFF  7077888ull           // 2 parities * 8 groups * 65536 = 1048576
#define FLG_OFF   8126464ull           // 8 groups * 32 u32 monotonic step flags
#define ST1_OFF   8159232ull           // 256*2 fp32 = 2048
#define ZERO_LEN  1083392ull           // hbuf + flags region + st1

__device__ __forceinline__ u16 f2bf(float f) {
  u32 u = __float_as_uint(f);
  u32 r = (u + 0x7FFFu + ((u >> 16) & 1u)) >> 16;
  return (u16)r;
}
__device__ __forceinline__ float bf2f(u16 h) {
  return __uint_as_float(((u32)h) << 16);
}
__device__ __forceinline__ float sigmf(float x) {
  float e = __expf(-fabsf(x));
  float s = 1.0f / (1.0f + e);
  return x >= 0.f ? s : 1.0f - s;
}
__device__ __forceinline__ float tanhf_(float x) {
  float e = __expf(-2.0f * fabsf(x));
  float t = (1.0f - e) / (1.0f + e);
  return x >= 0.f ? t : -t;
}
__device__ __forceinline__ frag8 pack_bf16(f4 a, f4 b) {
  union { u16 h[8]; frag8 f; } u;
  u.h[0] = f2bf(a[0]); u.h[1] = f2bf(a[1]); u.h[2] = f2bf(a[2]); u.h[3] = f2bf(a[3]);
  u.h[4] = f2bf(b[0]); u.h[5] = f2bf(b[1]); u.h[6] = f2bf(b[2]); u.h[7] = f2bf(b[3]);
  return u.f;
}

// fp32 -> bf16 weight conversion (W_hh then W_ih), exact-sized grid.
__global__ void prep_bf16(const float* __restrict__ whh_f32,
                          const float* __restrict__ wih_f32,
                          u16* __restrict__ whh, u16* __restrict__ wih) {
  int i = blockIdx.x * 256 + threadIdx.x;
  const int nhh = 3072 * 1024;
  if (i < nhh) whh[i] = f2bf(whh_f32[i]);
  else         wih[i - nhh] = f2bf(wih_f32[i - nhh]);
}

// 12 gi MFMAs (W_ih part) for the NEXT step, done between arrive and wait.
#define ACC_ZERO() do {                                                        \
  _Pragma("unroll") for (int bh_ = 0; bh_ < 2; ++bh_) {                        \
    _Pragma("unroll") for (int rt_ = 0; rt_ < 6; ++rt_) acc[bh_][rt_] = zz;    \
    accn[bh_][0] = zz; accn[bh_][1] = zz; }                                    \
} while (0)

#define IH_MFMA() do {                                                         \
  _Pragma("unroll") for (int rt_ = 0; rt_ < 4; ++rt_) {                        \
    acc[0][rt_] = __builtin_amdgcn_mfma_f32_16x16x32_bf16(smf0, wihf[rt_], acc[0][rt_], 0, 0, 0); \
    acc[1][rt_] = __builtin_amdgcn_mfma_f32_16x16x32_bf16(smf1, wihf[rt_], acc[1][rt_], 0, 0, 0); } \
  _Pragma("unroll") for (int nt_ = 0; nt_ < 2; ++nt_) {                        \
    accn[0][nt_] = __builtin_amdgcn_mfma_f32_16x16x32_bf16(smf0, wihf[4 + nt_], accn[0][nt_], 0, 0, 0); \
    accn[1][nt_] = __builtin_amdgcn_mfma_f32_16x16x32_bf16(smf1, wihf[4 + nt_], accn[1][nt_], 0, 0, 0); } \
} while (0)

// 24 hh MFMAs consuming af[2j], af[2j+1].
#define HH_CHUNK(j) do {                                                       \
  _Pragma("unroll") for (int kk_ = 0; kk_ < 2; ++kk_) {                        \
    const int kb_ = 2 * (j) + kk_;                                             \
    _Pragma("unroll") for (int rt_ = 0; rt_ < 6; ++rt_) {                      \
      acc[0][rt_] = __builtin_amdgcn_mfma_f32_16x16x32_bf16(af[kb_][0], whhf[kb_][rt_], acc[0][rt_], 0, 0, 0); \
      acc[1][rt_] = __builtin_amdgcn_mfma_f32_16x16x32_bf16(af[kb_][1], whhf[kb_][rt_], acc[1][rt_], 0, 0, 0); } } \
} while (0)

// 4 dwordx4 agent-coherent loads; issue order = vmcnt order (asm volatile keeps
// relative order among volatile asm). kb=2j(bh0,bh1), kb=2j+1(bh0,bh1).
#define AF_LOAD(j) asm volatile(                                               \
  "global_load_dwordx4 %0, %4, off sc0 sc1\n\t"                                \
  "global_load_dwordx4 %1, %4, off offset:1024 sc0 sc1\n\t"                    \
  "global_load_dwordx4 %2, %4, off offset:2048 sc0 sc1\n\t"                    \
  "global_load_dwordx4 %3, %4, off offset:3072 sc0 sc1"                        \
  : "=&v"(af[2 * (j)][0]), "=&v"(af[2 * (j)][1]),                              \
    "=&v"(af[2 * (j) + 1][0]), "=&v"(af[2 * (j) + 1][1])                       \
  : "v"(pb + (j) * 4096))

// Persistent GRU recurrence. 256 WGs = 8 groups (batch slices of 32) x 32 WGs
// (32 H-cols each). Flag-array barrier per step (no RMW serialization):
// arrival = one sc0/sc1 store of (t+1) into flags[g][w]; detection = 64-lane
// coalesced poll + ballot. EMA/pack/ih-MFMAs run between arrive and wait.
__global__ __launch_bounds__(256, 1) void gru_kernel(
    const float* __restrict__ x,       // [256][1024][128]
    const float* __restrict__ b_ih,    // [3072]
    const float* __restrict__ b_hh,    // [3072]
    const u16* __restrict__ whh,       // [3072][1024] bf16
    const u16* __restrict__ wih,       // [3072][128] bf16
    u64* __restrict__ hbuf,            // [2][8][8192] u64 (64KB per (p,g))
    u32* __restrict__ flags,           // [8][32] monotonic step counters
    float* __restrict__ st1)           // [256][2]
{
  __shared__ f4 xbuf[4096];            // 64 KB: [4 waves][128 gr][8 b-quads] swizzled
  const int wg = blockIdx.x;
  const int g = wg >> 5, w = wg & 31;
  const int tid = threadIdx.x;
  const int v = tid >> 6;              // wave = K-slice of 256
  const int l = tid & 63;
  const int lm = l & 15, lq = l >> 4;

  // ---- load weight fragments into registers (persistent) ----
  frag8 whhf[8][6];
  frag8 wihf[6];
#pragma unroll
  for (int rt = 0; rt < 6; ++rt) {
    int grow = (rt >> 1) * 1024 + w * 32 + (rt & 1) * 16 + lm;  // global gate row
    wihf[rt] = *(const frag8*)(wih + grow * 128 + v * 32 + lq * 8);
#pragma unroll
    for (int kb = 0; kb < 8; ++kb)
      whhf[kb][rt] = *(const frag8*)(whh + grow * 1024 + v * 256 + kb * 32 + lq * 8);
  }

  // ---- update-phase constants ----
  const int uc = tid & 31;
  const int ub0 = (tid >> 5) << 2;
  const int colg = w * 32 + uc;
  const float bir = b_ih[colg],         bhr = b_hh[colg];
  const float biz = b_ih[1024 + colg],  bhz = b_hh[1024 + colg];
  const float bin_ = b_ih[2048 + colg], bhn = b_hh[2048 + colg];
  f4 hprev = {0.f, 0.f, 0.f, 0.f};

  const float* xb0 = x + (size_t)(g * 32 + lm) * 131072 + v * 32 + lq * 8;
  const float* xb1 = x + (size_t)(g * 32 + 16 + lm) * 131072 + v * 32 + lq * 8;

  u32* flagbase = flags + (g << 5);
  u32* fself = flagbase + w;
  const f4 zz = {0.f, 0.f, 0.f, 0.f};
  const float A1 = 1.0f - ALPHA;

  // ---- prologue: EMA(0) = x(0); pack; gi(0) MFMAs ----
  f4 e0a = *(const f4*)xb0, e0b = *(const f4*)(xb0 + 4);
  f4 e1a = *(const f4*)xb1, e1b = *(const f4*)(xb1 + 4);
  frag8 smf0 = pack_bf16(e0a, e0b), smf1 = pack_bf16(e1a, e1b);
  f4 acc[2][6], accn[2][2];
  ACC_ZERO();
  IH_MFMA();

#pragma unroll 1
  for (int t = 0; t < 1024; ++t) {
    const char* hrd = (const char*)hbuf + ((size_t)((t & 1) * 8 + g) << 16);
    u64* hwrite = hbuf + (size_t)(((t + 1) & 1) * 8 + g) * 8192;

    // ---- issue h_t fragment loads (16x dwordx4, LLC) ----
    frag8 af[8][2];
    const char* pb = hrd + (v << 14) + (l << 4);
    AF_LOAD(0); AF_LOAD(1); AF_LOAD(2); AF_LOAD(3);

    // ---- issue x(t+1) prefetch (plain cached loads; consumed post-arrive) ----
    int tn = (t < 1023) ? t + 1 : 1023;  // clamp: last-iter loads are discarded
    const float* xp0 = xb0 + (size_t)tn * 128;
    const float* xp1 = xb1 + (size_t)tn * 128;
    f4 xa0n, xc0n, xa1n, xc1n;
    asm volatile(
      "global_load_dwordx4 %0, %4, off\n\t"
      "global_load_dwordx4 %1, %4, off offset:16\n\t"
      "global_load_dwordx4 %2, %5, off\n\t"
      "global_load_dwordx4 %3, %5, off offset:16"
      : "=&v"(xa0n), "=&v"(xc0n), "=&v"(xa1n), "=&v"(xc1n)
      : "v"(xp0), "v"(xp1));

    // ---- hh MFMAs in 4 chunks with counted vmcnt (vmcnt retires in order:
    //      outstanding = 16 af + 4 x = 20; chunk j needs loads 0..4j+3 done) ----
    asm volatile("s_waitcnt vmcnt(16)"); __builtin_amdgcn_sched_barrier(0);
    HH_CHUNK(0);
    asm volatile("s_waitcnt vmcnt(12)"); __builtin_amdgcn_sched_barrier(0);
    HH_CHUNK(1);
    asm volatile("s_waitcnt vmcnt(8)");  __builtin_amdgcn_sched_barrier(0);
    HH_CHUNK(2);
    asm volatile("s_waitcnt vmcnt(4)");  __builtin_amdgcn_sched_barrier(0);
    HH_CHUNK(3);

    // ---- write K-partials to LDS (transposed, XOR-swizzled, b128) ----
#pragma unroll
    for (int bh = 0; bh < 2; ++bh) {
      int b8 = bh * 4 + lq;
#pragma unroll
      for (int rt = 0; rt < 6; ++rt) {
        int gr = rt * 16 + lm;
        xbuf[((v * 128 + gr) << 3) | (b8 ^ (gr & 7))] = acc[bh][rt];
      }
#pragma unroll
      for (int nt = 0; nt < 2; ++nt) {
        int gr = 96 + nt * 16 + lm;
        xbuf[((v * 128 + gr) << 3) | (b8 ^ (gr & 7))] = accn[bh][nt];
      }
    }
    __syncthreads();   // (1) partials visible

    // ---- gate update: thread handles 4 batches (ub0..) x 1 col (uc) ----
    int swz = (ub0 >> 2) ^ (uc & 7);
    f4 sr = zz, sz4 = zz, gn4 = zz, gin4 = zz;
#pragma unroll
    for (int vv = 0; vv < 4; ++vv) {
      sr   += xbuf[((vv * 128 + uc) << 3) | swz];
      sz4  += xbuf[((vv * 128 + 32 + uc) << 3) | swz];
      gn4  += xbuf[((vv * 128 + 64 + uc) << 3) | swz];
      gin4 += xbuf[((vv * 128 + 96 + uc) << 3) | swz];
    }
    f4 h4;
#pragma unroll
    for (int i = 0; i < 4; ++i) {
      float rr = sigmf(sr[i] + bir + bhr);
      float zg = sigmf(sz4[i] + biz + bhz);
      float nn = tanhf_(gin4[i] + bin_ + rr * (gn4[i] + bhn));
      h4[i] = (1.0f - zg) * nn + zg * hprev[i];
    }
    hprev = h4;
    __syncthreads();   // (2) xbuf reads done, safe to reuse as staging

    // ---- stage h(bf16) in LDS, repack to 8B, store to hwrite ----
    u16* sbuf = (u16*)&xbuf[0];        // [32 b][stride 40]
#pragma unroll
    for (int i = 0; i < 4; ++i) sbuf[(ub0 + i) * 40 + uc] = f2bf(h4[i]);
    __syncthreads();   // (3)
    {
      int b = tid >> 3, c0 = (tid & 7) << 2;
      u64 pk = *(const u64*)(sbuf + b * 40 + c0);
      int off = ((w * 2 + (b >> 4)) * 64 + (b & 15) + 16 * (c0 >> 3)) * 2 + ((c0 & 7) >> 2);
      __hip_atomic_store(hwrite + off, pk, __ATOMIC_RELAXED, __HIP_MEMORY_SCOPE_AGENT);
    }
    asm volatile("s_waitcnt vmcnt(0)" ::: "memory");  // h stores at coherence point
    __syncthreads();   // (4) whole WG drained before signaling

    if (t < 1023) {
      // ---- arrive: fire-and-forget flag store (no RMW serialization) ----
      if (tid == 0)
        asm volatile("global_store_dword %0, %1, off sc0 sc1"
                     :: "v"(fself), "v"((u32)(t + 1)) : "memory");

      // x prefetch certainly retired (issued ~2us ago); wave0 skips its
      // in-flight flag store (vmcnt retires in order: flag is newest).
      if (tid < 64) asm volatile("s_waitcnt vmcnt(1)" ::: "memory");
      else          asm volatile("s_waitcnt vmcnt(0)" ::: "memory");
      __builtin_amdgcn_sched_barrier(0);

      // ---- overlapped with other WGs' arrival: EMA(t+1), pack, gi MFMAs ----
      e0a = A1 * xa0n + ALPHA * e0a; e0b = A1 * xc0n + ALPHA * e0b;
      e1a = A1 * xa1n + ALPHA * e1a; e1b = A1 * xc1n + ALPHA * e1b;
      if (t == 1022 && w == 0 && v == 0 && lq == 0) {
        // st_1 = EMA at t=1023; columns 1,2 for denorm
        st1[(g * 32 + lm) * 2 + 0] = e0a[1];
        st1[(g * 32 + lm) * 2 + 1] = e0a[2];
        st1[(g * 32 + 16 + lm) * 2 + 0] = e1a[1];
        st1[(g * 32 + 16 + lm) * 2 + 1] = e1a[2];
      }
      smf0 = pack_bf16(e0a, e0b); smf1 = pack_bf16(e1a, e1b);
      ACC_ZERO();
      IH_MFMA();

      // ---- wait: 64-lane coalesced poll of all 32 group flags ----
      if (tid < 64) {
        const u32* fp = flagbase + (tid & 31);
        while (1) {
          u32 fv;
          asm volatile("global_load_dword %0, %1, off sc0 sc1\n\t"
                       "s_waitcnt vmcnt(0)"
                       : "=v"(fv) : "v"(fp) : "memory");
          if (__ballot(fv > (u32)t) == ~0ull) break;
          __builtin_amdgcn_s_sleep(1);
        }
      }
      __syncthreads();   // (5) release whole WG into next step
    }
  }
}

// out[b][o] = (h_T[b] . W_fc[o] + b_fc[o] - a*st1[b][o]) / (1-a)
__global__ void fc_kernel(const u16* __restrict__ hbuf_bf,  // parity-0 region
                          const float* __restrict__ wfc,    // [2][1024]
                          const float* __restrict__ bfc,    // [2]
                          const float* __restrict__ st1,    // [256][2]
                          float* __restrict__ out)          // [256][2]
{
  int b = blockIdx.x, t = threadIdx.x;
  int g = b >> 5, bl = b & 31, bh = bl >> 4;
  int k0 = t * 4, kb = k0 >> 5, ko = k0 & 31;
  int lane = (bl & 15) + 16 * (ko >> 3);
  const u16* hp = hbuf_bf + (size_t)g * 32768 + ((kb * 2 + bh) * 64 + lane) * 8 + (ko & 7);
  float h0 = bf2f(hp[0]), h1 = bf2f(hp[1]), h2 = bf2f(hp[2]), h3 = bf2f(hp[3]);
  float s0 = h0 * wfc[k0] + h1 * wfc[k0 + 1] + h2 * wfc[k0 + 2] + h3 * wfc[k0 + 3];
  float s1 = h0 * wfc[1024 + k0] + h1 * wfc[1024 + k0 + 1] +
             h2 * wfc[1024 + k0 + 2] + h3 * wfc[1024 + k0 + 3];
#pragma unroll
  for (int off = 32; off > 0; off >>= 1) {
    s0 += __shfl_down(s0, off);
    s1 += __shfl_down(s1, off);
  }
  __shared__ float red[8];
  if ((t & 63) == 0) { red[(t >> 6) * 2] = s0; red[(t >> 6) * 2 + 1] = s1; }
  __syncthreads();
  if (t == 0) {
    float a0 = red[0] + red[2] + red[4] + red[6] + bfc[0];
    float a1 = red[1] + red[3] + red[5] + red[7] + bfc[1];
    float inv = 1.0f / (1.0f - ALPHA);
    out[b * 2 + 0] = (a0 - ALPHA * st1[b * 2 + 0]) * inv;
    out[b * 2 + 1] = (a1 - ALPHA * st1[b * 2 + 1]) * inv;
  }
}

extern "C" void kernel_launch(void* const* d_in, const int* in_sizes, int n_in,
                              void* d_out, int out_size, void* d_ws, size_t ws_size,
                              hipStream_t stream) {
  const float* x   = (const float*)d_in[0];
  const float* Wih = (const float*)d_in[1];
  const float* Whh = (const float*)d_in[2];
  const float* bih = (const float*)d_in[3];
  const float* bhh = (const float*)d_in[4];
  const float* Wfc = (const float*)d_in[5];
  const float* bfc = (const float*)d_in[6];
  char* ws = (char*)d_ws;
  u16* whh_bf = (u16*)(ws + WHH_OFF);
  u16* wih_bf = (u16*)(ws + WIH_OFF);
  u64* hbuf   = (u64*)(ws + HBUF_OFF);
  u32* flg    = (u32*)(ws + FLG_OFF);
  float* st1  = (float*)(ws + ST1_OFF);

  hipMemsetAsync(ws + HBUF_OFF, 0, ZERO_LEN, stream);
  prep_bf16<<<13824, 256, 0, stream>>>(Whh, Wih, whh_bf, wih_bf);
  gru_kernel<<<256, 256, 0, stream>>>(x, bih, bhh, whh_bf, wih_bf, hbuf, flg, st1);
  fc_kernel<<<256, 256, 0, stream>>>((const u16*)(ws + HBUF_OFF), Wfc, bfc, st1,
                                     (float*)d_out);
}